// Round 4
// baseline (410.614 us; speedup 1.0000x reference)
//
#include <hip/hip_runtime.h>

#define HW 409600
#define NCH 12

// workspace layout (bytes)
#define OFF_TACC   0        // 16*3 f32
#define OFF_KACC   256      // 80*3 f32
#define OFF_POS    2048     // 16 u32 each slot below
#define OFF_NEG    2112
#define OFF_MAXNK  2176
#define OFF_DONE   2240
#define OFF_FB     2304
#define OFF_NEGNUM 2368
#define OFF_THR    2432     // 16 f32
#define OFF_META_END 2496
#define OFF_MASK   4096     // 16*HW bytes = 6.25 MiB

__device__ __forceinline__ unsigned flipkey(float x){
  unsigned b = __float_as_uint(x);
  return (b & 0x80000000u) ? ~b : (b | 0x80000000u);   // monotone float->uint
}
__device__ __forceinline__ float unflip(unsigned u){
  unsigned b = (u & 0x80000000u) ? (u ^ 0x80000000u) : ~u;
  return __uint_as_float(b);
}
__device__ __forceinline__ float sigmoidf(float x){
  return __fdividef(1.0f, 1.0f + __expf(-x));
}

// K1: fused pass — counts + min-neg-key + text mask bytes (bit0=gt>0.5, bit1=tm>0.5)
//     + dice partial sums for the 5 kernel channels (mask = texts>0 && tm>0.5).
__global__ __launch_bounds__(256) void k_main(
    const float* __restrict__ outputs, const float* __restrict__ labels,
    const float* __restrict__ tmask, unsigned char* __restrict__ maskb,
    unsigned* __restrict__ posA, unsigned* __restrict__ negA,
    unsigned* __restrict__ maxnkA, float* __restrict__ kacc)
{
  int img = blockIdx.x & 15;        // img = ci*8 + bi ; interleave images across blocks
  int blk = blockIdx.x >> 4;        // 0..199
  int ci = img >> 3, bi = img & 7;
  const size_t chb = (size_t)(bi*NCH + ci*6)*HW;
  const float* tp = outputs + chb + (size_t)5*HW;
  const float* gp = labels  + chb + (size_t)5*HW;
  const float* mp = tmask   + (size_t)bi*HW;
  int base = blk*2048 + (int)threadIdx.x*4;   // two float4: base, base+1024

  // ---- phase 1: texts / gt_texts / tm ----
  float4 tv0 = *(const float4*)(tp+base);
  float4 tv1 = *(const float4*)(tp+base+1024);
  float4 gv0 = *(const float4*)(gp+base);
  float4 gv1 = *(const float4*)(gp+base+1024);
  float4 mv0 = *(const float4*)(mp+base);
  float4 mv1 = *(const float4*)(mp+base+1024);
  float tt[8]={tv0.x,tv0.y,tv0.z,tv0.w, tv1.x,tv1.y,tv1.z,tv1.w};
  float gg[8]={gv0.x,gv0.y,gv0.z,gv0.w, gv1.x,gv1.y,gv1.z,gv1.w};
  float mm[8]={mv0.x,mv0.y,mv0.z,mv0.w, mv1.x,mv1.y,mv1.z,mv1.w};

  unsigned pos=0, neg=0, mn=0xFFFFFFFFu, selk=0;
  unsigned char mb[8];
  #pragma unroll
  for (int c=0;c<8;c++){
    bool isneg = (gg[c] <= 0.5f);
    bool tpos  = (mm[c] > 0.5f);
    pos += (unsigned)((!isneg) && tpos);
    neg += (unsigned)isneg;
    if ((tt[c] > 0.0f) && tpos) selk |= (1u<<c);
    mb[c] = (unsigned char)((isneg ? 0u : 1u) | (tpos ? 2u : 0u));
    if (isneg){ unsigned k = flipkey(tt[c]); mn = (k<mn)?k:mn; }
  }
  unsigned char* mw = maskb + (size_t)img*HW + base;
  *(uchar4*)(mw)      = make_uchar4(mb[0],mb[1],mb[2],mb[3]);
  *(uchar4*)(mw+1024) = make_uchar4(mb[4],mb[5],mb[6],mb[7]);

  // ---- phase 2: 5 kernel channels, software-pipelined ----
  const float* kp = outputs + chb;
  const float* lp = labels  + chb;
  float ka[5], kb_[5], kc[5];
  float4 a0 = *(const float4*)(kp+base);
  float4 a1 = *(const float4*)(kp+base+1024);
  float4 b0 = *(const float4*)(lp+base);
  float4 b1 = *(const float4*)(lp+base+1024);
  #pragma unroll
  for (int j=0;j<5;j++){
    float4 na0,na1,nb0,nb1;
    if (j<4){
      const float* kpn = kp + (size_t)(j+1)*HW;
      const float* lpn = lp + (size_t)(j+1)*HW;
      na0 = *(const float4*)(kpn+base);
      na1 = *(const float4*)(kpn+base+1024);
      nb0 = *(const float4*)(lpn+base);
      nb1 = *(const float4*)(lpn+base+1024);
    }
    float pa[8]={a0.x,a0.y,a0.z,a0.w, a1.x,a1.y,a1.z,a1.w};
    float ga[8]={b0.x,b0.y,b0.z,b0.w, b1.x,b1.y,b1.z,b1.w};
    float sa=0.f, sb=0.f, sc=0.f;
    #pragma unroll
    for (int c=0;c<8;c++){
      float m = ((selk>>c)&1u) ? 1.0f : 0.0f;
      float p = m * sigmoidf(pa[c]);
      float t = ga[c]*m;
      sa += p*t; sb += p*p; sc += t*t;
    }
    ka[j]=sa; kb_[j]=sb; kc[j]=sc;
    if (j<4){ a0=na0; a1=na1; b0=nb0; b1=nb1; }
  }

  // ---- reductions ----
  #pragma unroll
  for (int o=32;o;o>>=1){
    #pragma unroll
    for (int j=0;j<5;j++){
      ka[j]  += __shfl_down(ka[j],o,64);
      kb_[j] += __shfl_down(kb_[j],o,64);
      kc[j]  += __shfl_down(kc[j],o,64);
    }
    pos += __shfl_down(pos,o,64);
    neg += __shfl_down(neg,o,64);
    unsigned om = __shfl_down(mn,o,64); mn = (om<mn)?om:mn;
  }
  __shared__ float sk[4][15];
  __shared__ unsigned spn[4][2], smn[4];
  int wv = threadIdx.x>>6, ln = threadIdx.x&63;
  if (ln==0){
    #pragma unroll
    for (int j=0;j<5;j++){ sk[wv][j]=ka[j]; sk[wv][5+j]=kb_[j]; sk[wv][10+j]=kc[j]; }
    spn[wv][0]=pos; spn[wv][1]=neg; smn[wv]=mn;
  }
  __syncthreads();
  if (threadIdx.x < 15){
    int j = threadIdx.x;
    float v = sk[0][j]+sk[1][j]+sk[2][j]+sk[3][j];
    int ch = j%5, comp = j/5;
    atomicAdd(&kacc[(img*5 + ch)*3 + comp], v);
  } else if (threadIdx.x == 32){
    atomicAdd(&posA[img], spn[0][0]+spn[1][0]+spn[2][0]+spn[3][0]);
    atomicAdd(&negA[img], spn[0][1]+spn[1][1]+spn[2][1]+spn[3][1]);
    unsigned m01 = (smn[0]<smn[1])?smn[0]:smn[1];
    unsigned m23 = (smn[2]<smn[3])?smn[2]:smn[3];
    unsigned m = (m01<m23)?m01:m23;
    atomicMax(&maxnkA[img], ~m);
  }
}

// K2: per-image decision — fallback / fast min-threshold / needs radix
__global__ void k_decide(
    const unsigned* __restrict__ posA, const unsigned* __restrict__ negA,
    const unsigned* __restrict__ maxnkA, unsigned* __restrict__ doneA,
    unsigned* __restrict__ fbA, unsigned* __restrict__ negnumA,
    float* __restrict__ thrA)
{
  int img = threadIdx.x;
  if (img >= 16) return;
  unsigned pos = posA[img], negt = negA[img];
  unsigned p3 = pos*3u;
  unsigned negnum = (p3 < negt) ? p3 : negt;
  if (pos==0u || negnum==0u){
    doneA[img]=1u; fbA[img]=1u; negnumA[img]=1u; thrA[img]=0.0f;
  } else if (negnum == negt){
    doneA[img]=1u; fbA[img]=0u; negnumA[img]=negnum;
    thrA[img] = unflip(~maxnkA[img]);                 // min negative score
  } else {
    doneA[img]=0u; fbA[img]=0u; negnumA[img]=negnum; thrA[img]=0.0f;
  }
}

// K3: generic OHEM radix threshold — one block per image, fully in-block
//     (3 rounds of 11/11/10-bit LDS histograms). Early-exits when doneA.
__global__ __launch_bounds__(1024) void k_fallback(
    const float* __restrict__ outputs, const unsigned char* __restrict__ maskb,
    const unsigned* __restrict__ doneA, const unsigned* __restrict__ negnumA,
    float* __restrict__ thrA)
{
  int img = blockIdx.x;
  if (doneA[img]) return;
  int ci=img>>3, bi=img&7;
  const float* tp = outputs + (size_t)(bi*NCH+ci*6+5)*HW;
  const unsigned char* mk = maskb + (size_t)img*HW;
  __shared__ unsigned lh[2048];
  __shared__ unsigned sel_s, krem_s;
  unsigned k = negnumA[img];
  unsigned prefix = 0;
  for (int round=0; round<3; round++){
    for (int j=threadIdx.x; j<2048; j+=1024) lh[j]=0u;
    __syncthreads();
    for (int it=0; it<100; it++){
      int px = it*4096 + (int)threadIdx.x*4;
      float4 tv = *(const float4*)(tp+px);
      uchar4 mq = *(const uchar4*)(mk+px);
      float tt[4]={tv.x,tv.y,tv.z,tv.w};
      unsigned char ma[4]={mq.x,mq.y,mq.z,mq.w};
      #pragma unroll
      for (int c=0;c<4;c++){
        if (!(ma[c]&1)){                       // negative: gt<=0.5
          unsigned key = flipkey(tt[c]);
          unsigned bin; bool ok;
          if (round==0){ bin = key>>21; ok = true; }
          else if (round==1){ ok = ((key>>21)==prefix); bin = (key>>10)&0x7FFu; }
          else { ok = ((key>>10)==prefix); bin = key & 0x3FFu; }
          if (ok) atomicAdd(&lh[bin], 1u);
        }
      }
    }
    __syncthreads();
    if (threadIdx.x==0){
      int nb = (round==2) ? 1024 : 2048;
      unsigned cum=0, sel=0, kr=1;
      for (int x=nb-1; x>=0; x--){
        cum += lh[x];
        if (cum >= k){ sel=(unsigned)x; kr = k - (cum - lh[x]); break; }
      }
      sel_s=sel; krem_s=kr;
    }
    __syncthreads();
    k = krem_s;
    prefix = (round==0) ? sel_s : ((prefix<<11) | sel_s);
    if (round==2 && threadIdx.x==0) thrA[img] = unflip((prefix<<10) >> 10 == prefix ? prefix : prefix); // placeholder, fixed below
    __syncthreads();
  }
  // after 3 rounds: prefix currently = ((key>>10)<<11 | sel3)? no — recompute:
  // round2 set prefix = (prefix22<<11)|sel3 which over-shifted; write correct key:
  if (threadIdx.x==0){
    // prefix after round1 was key>>10 (22 bits); round2 sel_s = low 10 bits
    unsigned p22 = prefix >> 11;          // undo round2's <<11
    unsigned sel3 = prefix & 0x7FFu;      // round2 sel (10 bits)
    thrA[img] = unflip((p22<<10) | sel3);
  }
}

// K4: text-channel dice (uses thr / fb / mask bytes; re-reads texts+gt_texts L3-warm)
__global__ __launch_bounds__(256) void k_text(
    const float* __restrict__ outputs, const float* __restrict__ labels,
    const float* __restrict__ tmask, const unsigned char* __restrict__ maskb,
    const unsigned* __restrict__ fbA, const float* __restrict__ thrA,
    float* __restrict__ tacc)
{
  int img = blockIdx.x & 15;
  int blk = blockIdx.x >> 4;
  int ci=img>>3, bi=img&7;
  const float* tp = outputs + (size_t)(bi*NCH+ci*6+5)*HW;
  const float* gp = labels  + (size_t)(bi*NCH+ci*6+5)*HW;
  const unsigned char* mk = maskb + (size_t)img*HW;
  int base = blk*2048 + (int)threadIdx.x*4;
  bool fb = (fbA[img] != 0u);
  float thr = thrA[img];

  float4 tv0 = *(const float4*)(tp+base);
  float4 tv1 = *(const float4*)(tp+base+1024);
  float4 gv0 = *(const float4*)(gp+base);
  float4 gv1 = *(const float4*)(gp+base+1024);
  uchar4 m0 = *(const uchar4*)(mk+base);
  uchar4 m1 = *(const uchar4*)(mk+base+1024);
  float tt[8]={tv0.x,tv0.y,tv0.z,tv0.w, tv1.x,tv1.y,tv1.z,tv1.w};
  float gg[8]={gv0.x,gv0.y,gv0.z,gv0.w, gv1.x,gv1.y,gv1.z,gv1.w};
  unsigned char ma[8]={m0.x,m0.y,m0.z,m0.w, m1.x,m1.y,m1.z,m1.w};
  float ta[8]={0,0,0,0,0,0,0,0};
  if (fb){
    const float* mp = tmask + (size_t)bi*HW;
    float4 x0 = *(const float4*)(mp+base);
    float4 x1 = *(const float4*)(mp+base+1024);
    ta[0]=x0.x;ta[1]=x0.y;ta[2]=x0.z;ta[3]=x0.w;
    ta[4]=x1.x;ta[5]=x1.y;ta[6]=x1.z;ta[7]=x1.w;
  }
  float sa=0.f, sb=0.f, sc=0.f;
  #pragma unroll
  for (int c=0;c<8;c++){
    float m;
    if (fb) m = ta[c];
    else    m = (((tt[c] >= thr) || (ma[c]&1)) && (ma[c]&2)) ? 1.0f : 0.0f;
    float p = m * sigmoidf(tt[c]);
    float t = gg[c]*m;
    sa += p*t; sb += p*p; sc += t*t;
  }
  #pragma unroll
  for (int o=32;o;o>>=1){
    sa += __shfl_down(sa,o,64); sb += __shfl_down(sb,o,64); sc += __shfl_down(sc,o,64);
  }
  __shared__ float ra[4], rb[4], rc[4];
  int wv=threadIdx.x>>6, ln=threadIdx.x&63;
  if (ln==0){ ra[wv]=sa; rb[wv]=sb; rc[wv]=sc; }
  __syncthreads();
  if (threadIdx.x==0){
    atomicAdd(&tacc[img*3+0], ra[0]+ra[1]+ra[2]+ra[3]);
    atomicAdd(&tacc[img*3+1], rb[0]+rb[1]+rb[2]+rb[3]);
    atomicAdd(&tacc[img*3+2], rc[0]+rc[1]+rc[2]+rc[3]);
  }
}

// K5: finalize 3 outputs
__global__ void k_final(const float* __restrict__ tacc, const float* __restrict__ kacc,
                        float* __restrict__ out)
{
  if (blockIdx.x==0 && threadIdx.x==0){
    const float EPSF = 1e-4f;
    float ltA[2], lkA[2];
    for (int i=0;i<2;i++){
      float lt=0.f;
      for (int b=0;b<8;b++){
        int img=i*8+b;
        float a=tacc[img*3], p2=tacc[img*3+1]+EPSF, t2=tacc[img*3+2]+EPSF;
        lt += 1.f - 2.f*a/(p2+t2);
      }
      lt *= 0.125f;
      float lk=0.f;
      for (int b=0;b<8;b++) for (int k=0;k<5;k++){
        int idx=((i*8+b)*5+k)*3;
        float a=kacc[idx], p2=kacc[idx+1]+EPSF, t2=kacc[idx+2]+EPSF;
        lk += 1.f - 2.f*a/(p2+t2);
      }
      lk /= 40.f;
      ltA[i]=lt; lkA[i]=lk;
    }
    float l0 = 0.7f*ltA[0] + 0.3f*lkA[0];
    float l1 = 0.7f*ltA[1] + 0.3f*lkA[1];
    out[0]=0.5f*(l0+l1);
    out[1]=0.5f*(ltA[0]+ltA[1]);
    out[2]=0.5f*(lkA[0]+lkA[1]);
  }
}

extern "C" void kernel_launch(void* const* d_in, const int* in_sizes, int n_in,
                              void* d_out, int out_size, void* d_ws, size_t ws_size,
                              hipStream_t stream)
{
  const float* outputs = (const float*)d_in[0];
  const float* labels  = (const float*)d_in[1];
  const float* tmask   = (const float*)d_in[2];
  float* out = (float*)d_out;
  char* ws = (char*)d_ws;
  float* tacc      = (float*)(ws + OFF_TACC);
  float* kacc      = (float*)(ws + OFF_KACC);
  unsigned* posA   = (unsigned*)(ws + OFF_POS);
  unsigned* negA   = (unsigned*)(ws + OFF_NEG);
  unsigned* maxnkA = (unsigned*)(ws + OFF_MAXNK);
  unsigned* doneA  = (unsigned*)(ws + OFF_DONE);
  unsigned* fbA    = (unsigned*)(ws + OFF_FB);
  unsigned* negnumA= (unsigned*)(ws + OFF_NEGNUM);
  float* thrA      = (float*)(ws + OFF_THR);
  unsigned char* maskb = (unsigned char*)(ws + OFF_MASK);

  hipMemsetAsync(ws, 0, OFF_META_END, stream);   // accumulators + meta only (~2.5 KB)
  k_main    <<<3200,256,0,stream>>>(outputs, labels, tmask, maskb, posA, negA, maxnkA, kacc);
  k_decide  <<<1,64,0,stream>>>(posA, negA, maxnkA, doneA, fbA, negnumA, thrA);
  k_fallback<<<16,1024,0,stream>>>(outputs, maskb, doneA, negnumA, thrA);
  k_text    <<<3200,256,0,stream>>>(outputs, labels, tmask, maskb, fbA, thrA, tacc);
  k_final   <<<1,64,0,stream>>>(tacc, kacc, out);
}